// Round 1
// baseline (56.677 us; speedup 1.0000x reference)
//
#include <hip/hip_runtime.h>
#include <hip/hip_bf16.h>

typedef __bf16 bf16x8 __attribute__((ext_vector_type(8)));
typedef __bf16 bf16x4 __attribute__((ext_vector_type(4)));
typedef float  f32x4  __attribute__((ext_vector_type(4)));

#define B_ 256
#define N_ 256
#define D_ 128
#define PSRC 136                                  // row-major LDS pitch (bf16 elems)
#define OFF_SRCT (N_ * PSRC * 2)                  // 69632
#define OFF_ALPHA (OFF_SRCT + D_ * 512)           // 135168
#define PALPHA 72
#define LDS_BYTES (OFF_ALPHA + 8 * 16 * PALPHA * 2)  // 153600

__global__ __launch_bounds__(512, 2) void gat_fused(
    const float* __restrict__ src, const int* __restrict__ adj,
    const float* __restrict__ a0, const float* __restrict__ a1,
    const float* __restrict__ a2, const float* __restrict__ a3,
    const float* __restrict__ bias, float* __restrict__ out)
{
    extern __shared__ char lds[];
    __bf16* s_src  = (__bf16*)lds;                // [256][136] bf16 row-major
    char*   s_srcT = lds + OFF_SRCT;              // [128][256] bf16, XOR-swizzled rows
    const int t    = threadIdx.x;
    const int lane = t & 63;
    const int wave = t >> 6;
    const int g    = lane >> 4;                   // 0..3
    const int r16  = lane & 15;                   // 0..15
    __bf16* s_alpha = (__bf16*)(lds + OFF_ALPHA) + wave * (16 * PALPHA);

    const int b = blockIdx.x;
    const float* __restrict__ srcb = src + (size_t)b * (N_ * D_);
    const int*   __restrict__ adjb = adj + (size_t)b * (N_ * N_);
    float*       __restrict__ outb = out + (size_t)b * (N_ * D_);

    // ---------------- stage src[b]: row-major bf16 + swizzled transpose ----------------
    {
        const int d   = t & 127;
        const int jb  = (t >> 7) * 64;
        const int swz = (d & 7) << 4;
        #pragma unroll
        for (int jj = 0; jj < 64; jj += 4) {
            bf16x4 w;
            #pragma unroll
            for (int q = 0; q < 4; ++q) {
                const int j = jb + jj + q;
                const __bf16 h = (__bf16)srcb[j * D_ + d];
                s_src[j * PSRC + d] = h;          // coalesced b16, conflict-free
                w[q] = h;
            }
            const int j0 = jb + jj;
            *(bf16x4*)(s_srcT + (d * 512 + ((2 * j0) ^ swz))) = w;  // b64, 8-way (once)
        }
    }
    __syncthreads();

    // bias per-lane (cached)
    float bv[8];
    #pragma unroll
    for (int dt = 0; dt < 8; ++dt) bv[dt] = bias[dt * 16 + r16];

    const float* __restrict__ aptr[4] = {a0, a1, a2, a3};

    #pragma unroll 1
    for (int half = 0; half < 2; ++half) {
        const int i0 = half * 128 + wave * 16;    // this wave's 16 output rows

        // ---- A-fragments: bf16(src[i,:] * a_k), 4 k x 4 K-chunks ----
        bf16x8 asf[4][4];
        #pragma unroll
        for (int kc = 0; kc < 4; ++kc) {
            const bf16x8 base = *(const bf16x8*)&s_src[(i0 + r16) * PSRC + kc * 32 + g * 8];
            float bf[8];
            #pragma unroll
            for (int e = 0; e < 8; ++e) bf[e] = (float)base[e];
            #pragma unroll
            for (int k = 0; k < 4; ++k) {
                const float4 av0 = *(const float4*)(aptr[k] + kc * 32 + g * 8);
                const float4 av1 = *(const float4*)(aptr[k] + kc * 32 + g * 8 + 4);
                bf16x8 f;
                f[0] = (__bf16)(bf[0] * av0.x); f[1] = (__bf16)(bf[1] * av0.y);
                f[2] = (__bf16)(bf[2] * av0.z); f[3] = (__bf16)(bf[3] * av0.w);
                f[4] = (__bf16)(bf[4] * av1.x); f[5] = (__bf16)(bf[5] * av1.y);
                f[6] = (__bf16)(bf[6] * av1.z); f[7] = (__bf16)(bf[7] * av1.w);
                asf[k][kc] = f;
            }
        }

        // ---- QK^T (4 scaled variants) + adj-select + leaky_relu ----
        float p[16][4];                            // logits, then probabilities
        int adjn[4];
        {
            const int* ap = adjb + (i0 + g * 4) * N_ + r16;
            adjn[0] = ap[0]; adjn[1] = ap[N_]; adjn[2] = ap[2 * N_]; adjn[3] = ap[3 * N_];
        }
        #pragma unroll
        for (int jt = 0; jt < 16; ++jt) {
            int adjc[4];
            adjc[0] = adjn[0]; adjc[1] = adjn[1]; adjc[2] = adjn[2]; adjc[3] = adjn[3];
            if (jt < 15) {                         // depth-1 prefetch of next adj tile
                const int* ap = adjb + (i0 + g * 4) * N_ + (jt + 1) * 16 + r16;
                adjn[0] = ap[0]; adjn[1] = ap[N_]; adjn[2] = ap[2 * N_]; adjn[3] = ap[3 * N_];
            }
            bf16x8 bfr[4];
            #pragma unroll
            for (int kc = 0; kc < 4; ++kc)
                bfr[kc] = *(const bf16x8*)&s_src[(jt * 16 + r16) * PSRC + kc * 32 + g * 8];
            f32x4 acc0 = {0,0,0,0}, acc1 = {0,0,0,0}, acc2 = {0,0,0,0}, acc3 = {0,0,0,0};
            #pragma unroll
            for (int kc = 0; kc < 4; ++kc) {
                acc0 = __builtin_amdgcn_mfma_f32_16x16x32_bf16(asf[0][kc], bfr[kc], acc0, 0, 0, 0);
                acc1 = __builtin_amdgcn_mfma_f32_16x16x32_bf16(asf[1][kc], bfr[kc], acc1, 0, 0, 0);
                acc2 = __builtin_amdgcn_mfma_f32_16x16x32_bf16(asf[2][kc], bfr[kc], acc2, 0, 0, 0);
                acc3 = __builtin_amdgcn_mfma_f32_16x16x32_bf16(asf[3][kc], bfr[kc], acc3, 0, 0, 0);
            }
            #pragma unroll
            for (int rr = 0; rr < 4; ++rr) {
                float v = -3.402823466e38f;        // neg sentinel (lrelu keeps it huge-neg)
                const int a = adjc[rr];
                v = (a == 1) ? acc0[rr] : v;
                v = (a == 2) ? acc1[rr] : v;
                v = (a == 3) ? acc2[rr] : v;
                v = (a == 4) ? acc3[rr] : v;
                p[jt][rr] = fmaxf(v, 0.2f * v);    // leaky_relu(x) = max(x, 0.2x)
            }
        }

        // ---- row softmax (reduce over the 16 n-lanes, masks 1/2/4/8) ----
        float scale[4];
        #pragma unroll
        for (int rr = 0; rr < 4; ++rr) {
            float mm = p[0][rr];
            #pragma unroll
            for (int jt = 1; jt < 16; ++jt) mm = fmaxf(mm, p[jt][rr]);
            mm = fmaxf(mm, __shfl_xor(mm, 1));
            mm = fmaxf(mm, __shfl_xor(mm, 2));
            mm = fmaxf(mm, __shfl_xor(mm, 4));
            mm = fmaxf(mm, __shfl_xor(mm, 8));
            float s = 0.f;
            #pragma unroll
            for (int jt = 0; jt < 16; ++jt) {
                const float e = __builtin_exp2f((p[jt][rr] - mm) * 1.4426950408889634f);
                p[jt][rr] = e;
                s += e;
            }
            s += __shfl_xor(s, 1);
            s += __shfl_xor(s, 2);
            s += __shfl_xor(s, 4);
            s += __shfl_xor(s, 8);
            scale[rr] = 1.0f / s;                  // normalize at epilogue
        }

        // ---- PV: out = (p @ src) * scale, chunked through per-wave LDS alpha buffer ----
        f32x4 oacc[8];
        #pragma unroll
        for (int dt = 0; dt < 8; ++dt) oacc[dt] = (f32x4){0, 0, 0, 0};
        #pragma unroll
        for (int c = 0; c < 4; ++c) {
            asm volatile("s_waitcnt lgkmcnt(0)" ::: "memory");  // WAR vs prior chunk reads
            #pragma unroll
            for (int tt = 0; tt < 4; ++tt) {
                #pragma unroll
                for (int rr = 0; rr < 4; ++rr)
                    s_alpha[(g * 4 + rr) * PALPHA + tt * 16 + r16] = (__bf16)p[c * 4 + tt][rr];
            }
            asm volatile("s_waitcnt lgkmcnt(0)" ::: "memory");  // RAW: writes visible
            #pragma unroll
            for (int s = 0; s < 2; ++s) {
                const bf16x8 af = *(const bf16x8*)&s_alpha[r16 * PALPHA + s * 32 + g * 8];
                #pragma unroll
                for (int dt = 0; dt < 8; ++dt) {
                    const int d    = dt * 16 + r16;
                    const int jcol = c * 64 + s * 32 + g * 8;
                    const bf16x8 vf = *(const bf16x8*)(s_srcT +
                        (d * 512 + ((2 * jcol) ^ ((d & 7) << 4))));
                    oacc[dt] = __builtin_amdgcn_mfma_f32_16x16x32_bf16(af, vf, oacc[dt], 0, 0, 0);
                }
            }
        }

        // ---- epilogue: scale + bias, coalesced f32 stores ----
        #pragma unroll
        for (int dt = 0; dt < 8; ++dt) {
            #pragma unroll
            for (int rr = 0; rr < 4; ++rr) {
                outb[(i0 + g * 4 + rr) * D_ + dt * 16 + r16] = oacc[dt][rr] * scale[rr] + bv[dt];
            }
        }
    }
}

extern "C" void kernel_launch(void* const* d_in, const int* in_sizes, int n_in,
                              void* d_out, int out_size, void* d_ws, size_t ws_size,
                              hipStream_t stream) {
    const float* src  = (const float*)d_in[0];
    const int*   adj  = (const int*)d_in[1];
    const float* a0   = (const float*)d_in[2];
    const float* a1   = (const float*)d_in[3];
    const float* a2   = (const float*)d_in[4];
    const float* a3   = (const float*)d_in[5];
    const float* bias = (const float*)d_in[6];
    float* out = (float*)d_out;

    (void)hipFuncSetAttribute((const void*)gat_fused,
                              hipFuncAttributeMaxDynamicSharedMemorySize, LDS_BYTES);
    gat_fused<<<B_, 512, LDS_BYTES, stream>>>(src, adj, a0, a1, a2, a3, bias, out);
}